// Round 1
// baseline (281.408 us; speedup 1.0000x reference)
//
#include <hip/hip_runtime.h>

#define K_CODES   8192
#define N_PIX     16384
#define D_DIM     64
#define EM_STRIDE 8193   // embed row stride (K+1)
#define KB_SPLIT  64     // k-blocks of 128 codes
#define OUT_QUANT 0
#define OUT_DMIN  1048576
#define OUT_IND   (1048576 + 16384)

// ---------------------------------------------------------------------------
// Kernel 1: per-code squared norms, stale codes pushed to +huge so they are
// never selected (matches reference's STALE_VAL=9990 masking semantics: stale
// distances ~6.4e9 can never be the min).
// ---------------------------------------------------------------------------
__global__ __launch_bounds__(256)
void vq_code_norms(const float* __restrict__ embed,
                   const int* __restrict__ cnt,
                   float* __restrict__ cn) {
    int k = blockIdx.x * 256 + threadIdx.x;
    if (k >= K_CODES) return;
    float s = 0.f;
#pragma unroll
    for (int d = 0; d < D_DIM; ++d) {
        float v = embed[d * EM_STRIDE + k];
        s = fmaf(v, v, s);
    }
    cn[k] = (cnt[k] < 1) ? 1.0e30f : s;
}

// ---------------------------------------------------------------------------
// Kernel 2: tiled fp32 "GEMM" + fused partial argmin.
// Block = 256 threads, tile = 128 rows x 128 codes, full D=64 reduction.
// Per-thread micro-tile 8x8 (rows {4g..4g+3, +64}, codes {4j..4j+3, +64}).
// Stores per-(kblock,row) partial (min dist without ||x||^2, argmin idx).
// ---------------------------------------------------------------------------
__global__ __launch_bounds__(256)
void vq_dist_tile(const float* __restrict__ x,     // [64][16384]
                  const float* __restrict__ e,     // [64][8193]
                  const float* __restrict__ cn,    // [8192] masked norms
                  float* __restrict__ pmin,        // [64][16384]
                  int*   __restrict__ pidx) {      // [64][16384]
    __shared__ float xs[D_DIM][128];
    __shared__ float es[D_DIM][128];

    const int nb = blockIdx.x & 127;   // 128 row blocks
    const int kb = blockIdx.x >> 7;    // 64 code blocks
    const int n0 = nb * 128;
    const int k0 = kb * 128;
    const int t  = threadIdx.x;

    // ---- stage x tile: 64x128 floats, float4, fully coalesced ----
#pragma unroll
    for (int s = 0; s < 8; ++s) {
        int q  = s * 256 + t;          // quad index 0..2047
        int d  = q >> 5;               // 32 quads per row
        int i4 = (q & 31) << 2;
        *(float4*)&xs[d][i4] = *(const float4*)&x[d * N_PIX + n0 + i4];
    }
    // ---- stage e tile: scalar loads (row stride 8193 breaks 16B align) ----
#pragma unroll
    for (int s = 0; s < 32; ++s) {
        int q = s * 256 + t;           // 0..8191
        int d = q >> 7;
        int j = q & 127;
        es[d][j] = e[d * EM_STRIDE + k0 + j];
    }
    __syncthreads();

    const int g  = t >> 4;             // 0..15 row group
    const int jj = t & 15;             // 0..15 code lane
    const int g4 = g * 4;
    const int j4 = jj * 4;

    float acc[8][8];
#pragma unroll
    for (int r = 0; r < 8; ++r)
#pragma unroll
        for (int c = 0; c < 8; ++c) acc[r][c] = 0.f;

#pragma unroll 4
    for (int d = 0; d < D_DIM; ++d) {
        float4 t0 = *(const float4*)&xs[d][g4];
        float4 t1 = *(const float4*)&xs[d][g4 + 64];
        float4 t2 = *(const float4*)&es[d][j4];
        float4 t3 = *(const float4*)&es[d][j4 + 64];
        float a[8] = {t0.x, t0.y, t0.z, t0.w, t1.x, t1.y, t1.z, t1.w};
        float b[8] = {t2.x, t2.y, t2.z, t2.w, t3.x, t3.y, t3.z, t3.w};
#pragma unroll
        for (int r = 0; r < 8; ++r)
#pragma unroll
            for (int c = 0; c < 8; ++c)
                acc[r][c] = fmaf(a[r], b[c], acc[r][c]);
    }

    // ---- epilogue: dist = cn[k] - 2*dot ; per-row argmin over 8 codes,
    //      then butterfly-min across the 16 code lanes of this row group ----
    float cnv[8];
#pragma unroll
    for (int c = 0; c < 8; ++c) {
        int k = k0 + j4 + ((c < 4) ? c : 60 + c);   // c=4..7 -> +64..+67
        cnv[c] = cn[k];
    }

#pragma unroll
    for (int r = 0; r < 8; ++r) {
        float bd  = 3.0e38f;
        int   bix = 0;
#pragma unroll
        for (int c = 0; c < 8; ++c) {               // ascending k: strict <
            float dist = fmaf(-2.f, acc[r][c], cnv[c]);
            int   k    = k0 + j4 + ((c < 4) ? c : 60 + c);
            if (dist < bd) { bd = dist; bix = k; }
        }
        // reduce across 16 code lanes (xor stays within the 16-lane group)
#pragma unroll
        for (int m = 1; m < 16; m <<= 1) {
            float od = __shfl_xor(bd, m, 64);
            int   oi = __shfl_xor(bix, m, 64);
            if (od < bd || (od == bd && oi < bix)) { bd = od; bix = oi; }
        }
        if (jj == 0) {
            int lr = (r < 4) ? (g4 + r) : (64 + g4 + r - 4);
            pmin[kb * N_PIX + n0 + lr] = bd;
            pidx[kb * N_PIX + n0 + lr] = bix;
        }
    }
}

// ---------------------------------------------------------------------------
// Kernel 3: reduce 64 k-block partials per row, add ||x||^2, gather winning
// code column, write all three outputs (quant [64][16384], dmin, idx-as-f32).
// ---------------------------------------------------------------------------
__global__ __launch_bounds__(256)
void vq_finalize(const float* __restrict__ x,
                 const float* __restrict__ e,
                 const float* __restrict__ pmin,
                 const int*   __restrict__ pidx,
                 float* __restrict__ out) {
    int n = blockIdx.x * 256 + threadIdx.x;   // 0..16383
    float best = 3.0e38f;
    int   bi   = 0x7fffffff;
#pragma unroll 4
    for (int kb = 0; kb < KB_SPLIT; ++kb) {
        float m = pmin[kb * N_PIX + n];
        int   i = pidx[kb * N_PIX + n];
        if (m < best || (m == best && i < bi)) { best = m; bi = i; }
    }
    float rn = 0.f;
#pragma unroll
    for (int d = 0; d < D_DIM; ++d) {
        float v = x[d * N_PIX + n];
        rn = fmaf(v, v, rn);
    }
    out[OUT_DMIN + n] = best + rn;
    out[OUT_IND  + n] = (float)bi;
#pragma unroll
    for (int d = 0; d < D_DIM; ++d)
        out[OUT_QUANT + d * N_PIX + n] = e[d * EM_STRIDE + bi];
}

// ---------------------------------------------------------------------------
extern "C" void kernel_launch(void* const* d_in, const int* in_sizes, int n_in,
                              void* d_out, int out_size, void* d_ws, size_t ws_size,
                              hipStream_t stream) {
    const float* x     = (const float*)d_in[0];   // [1,64,128,128]
    const float* embed = (const float*)d_in[1];   // [64,8193]
    const int*   cnt   = (const int*)d_in[2];     // [8192]
    float* out = (float*)d_out;

    // workspace layout
    float* pmin = (float*)d_ws;                                    // 4 MB
    int*   pidx = (int*)((char*)d_ws + (size_t)KB_SPLIT * N_PIX * 4); // 4 MB
    float* cn   = (float*)((char*)d_ws + (size_t)KB_SPLIT * N_PIX * 8); // 32 KB

    vq_code_norms<<<(K_CODES + 255) / 256, 256, 0, stream>>>(embed, cnt, cn);
    vq_dist_tile<<<KB_SPLIT * 128, 256, 0, stream>>>(x, embed, cn, pmin, pidx);
    vq_finalize<<<N_PIX / 256, 256, 0, stream>>>(x, embed, pmin, pidx, out);
}

// Round 2
// 254.980 us; speedup vs baseline: 1.1036x; 1.1036x over previous
//
#include <hip/hip_runtime.h>

#define K_CODES   8192
#define N_PIX     16384
#define D_DIM     64
#define EM_STRIDE 8193   // original embed row stride (K+1)
#define KSUB      8      // 128-code subtiles per block (k-persistence)
#define KGRP      8      // k-groups = 8192 / (KSUB*128)
#define OUT_QUANT 0
#define OUT_DMIN  1048576
#define OUT_IND   (1048576 + 16384)

// ---------------------------------------------------------------------------
// Kernel 1: per-code squared norms (stale -> +huge, never selected) and a
// stride-8192 copy of embed so tile staging can use aligned float4 loads.
// ---------------------------------------------------------------------------
__global__ __launch_bounds__(256)
void vq_prep(const float* __restrict__ embed,
             const int* __restrict__ cnt,
             float* __restrict__ ec,     // [64][8192]
             float* __restrict__ cn) {   // [8192]
    int k = blockIdx.x * 256 + threadIdx.x;
    float s = 0.f;
#pragma unroll
    for (int d = 0; d < D_DIM; ++d) {
        float v = embed[d * EM_STRIDE + k];
        ec[d * K_CODES + k] = v;
        s = fmaf(v, v, s);
    }
    cn[k] = (cnt[k] < 1) ? 1.0e30f : s;
}

// ---------------------------------------------------------------------------
// Kernel 2: fp32 distance GEMM + fused running argmin.
// Block = 256 thr, covers 128 rows x 1024 codes (8 subtiles of 128 codes).
// LDS is d-chunked (32 of 64 rows at a time) -> 32 KB -> 4 blocks/CU.
// Per-thread 8x8 micro-tile; running (best,idx) kept in registers across
// subtiles; one shuffle-reduce + partial write per block.
// ---------------------------------------------------------------------------
__global__ __launch_bounds__(256, 4)
void vq_dist_tile(const float* __restrict__ x,     // [64][16384]
                  const float* __restrict__ ec,    // [64][8192]
                  const float* __restrict__ cn,    // [8192] masked norms
                  float* __restrict__ pmin,        // [KGRP][16384]
                  int*   __restrict__ pidx) {      // [KGRP][16384]
    __shared__ float xs[32][128];
    __shared__ float es[32][128];

    const int nb = blockIdx.x & 127;   // 128 row blocks
    const int kg = blockIdx.x >> 7;    // 8 k-groups of 1024 codes
    const int n0 = nb * 128;
    const int kgb = kg * (KSUB * 128);
    const int t  = threadIdx.x;

    // staging decomposition: thread t covers float4 #q = s*256+t, s=0..3
    const int sd = t >> 5;             // row-within-group contribution (0..7)
    const int sc = (t & 31) << 2;      // col (float) 0..124

    const int g  = t >> 4;             // 0..15 row group
    const int jj = t & 15;             // 0..15 code lane
    const int g4 = g * 4;
    const int j4 = jj * 4;

    float acc[8][8];
    float bd[8];
    int   bix[8];
#pragma unroll
    for (int r = 0; r < 8; ++r) {
        bd[r] = 3.0e38f; bix[r] = 0;
#pragma unroll
        for (int c = 0; c < 8; ++c) acc[r][c] = 0.f;
    }

    const float* xsp = &xs[0][g4];
    const float* esp = &es[0][j4];

    for (int st = 0; st < KSUB; ++st) {
        const int k0 = kgb + st * 128;

        for (int ch = 0; ch < 2; ++ch) {
            const int d0 = ch * 32;
            __syncthreads();           // previous tile fully consumed
            // ---- stage x chunk + e chunk (float4, fully coalesced) ----
#pragma unroll
            for (int s = 0; s < 4; ++s) {
                int dd = d0 + s * 8 + sd;
                float4 vx = *(const float4*)&x [dd * N_PIX   + n0 + sc];
                float4 ve = *(const float4*)&ec[dd * K_CODES + k0 + sc];
                *(float4*)&xs[s * 8 + sd][sc] = vx;
                *(float4*)&es[s * 8 + sd][sc] = ve;
            }
            __syncthreads();
            // ---- compute: 32 d-steps, 64 FMA each ----
#pragma unroll 8
            for (int d = 0; d < 32; ++d) {
                float4 xa = *(const float4*)(xsp + d * 128);
                float4 xb = *(const float4*)(xsp + d * 128 + 64);
                float4 ea = *(const float4*)(esp + d * 128);
                float4 eb = *(const float4*)(esp + d * 128 + 64);
                acc[0][0] = fmaf(xa.x, ea.x, acc[0][0]);
                acc[0][1] = fmaf(xa.x, ea.y, acc[0][1]);
                acc[0][2] = fmaf(xa.x, ea.z, acc[0][2]);
                acc[0][3] = fmaf(xa.x, ea.w, acc[0][3]);
                acc[0][4] = fmaf(xa.x, eb.x, acc[0][4]);
                acc[0][5] = fmaf(xa.x, eb.y, acc[0][5]);
                acc[0][6] = fmaf(xa.x, eb.z, acc[0][6]);
                acc[0][7] = fmaf(xa.x, eb.w, acc[0][7]);
                acc[1][0] = fmaf(xa.y, ea.x, acc[1][0]);
                acc[1][1] = fmaf(xa.y, ea.y, acc[1][1]);
                acc[1][2] = fmaf(xa.y, ea.z, acc[1][2]);
                acc[1][3] = fmaf(xa.y, ea.w, acc[1][3]);
                acc[1][4] = fmaf(xa.y, eb.x, acc[1][4]);
                acc[1][5] = fmaf(xa.y, eb.y, acc[1][5]);
                acc[1][6] = fmaf(xa.y, eb.z, acc[1][6]);
                acc[1][7] = fmaf(xa.y, eb.w, acc[1][7]);
                acc[2][0] = fmaf(xa.z, ea.x, acc[2][0]);
                acc[2][1] = fmaf(xa.z, ea.y, acc[2][1]);
                acc[2][2] = fmaf(xa.z, ea.z, acc[2][2]);
                acc[2][3] = fmaf(xa.z, ea.w, acc[2][3]);
                acc[2][4] = fmaf(xa.z, eb.x, acc[2][4]);
                acc[2][5] = fmaf(xa.z, eb.y, acc[2][5]);
                acc[2][6] = fmaf(xa.z, eb.z, acc[2][6]);
                acc[2][7] = fmaf(xa.z, eb.w, acc[2][7]);
                acc[3][0] = fmaf(xa.w, ea.x, acc[3][0]);
                acc[3][1] = fmaf(xa.w, ea.y, acc[3][1]);
                acc[3][2] = fmaf(xa.w, ea.z, acc[3][2]);
                acc[3][3] = fmaf(xa.w, ea.w, acc[3][3]);
                acc[3][4] = fmaf(xa.w, eb.x, acc[3][4]);
                acc[3][5] = fmaf(xa.w, eb.y, acc[3][5]);
                acc[3][6] = fmaf(xa.w, eb.z, acc[3][6]);
                acc[3][7] = fmaf(xa.w, eb.w, acc[3][7]);
                acc[4][0] = fmaf(xb.x, ea.x, acc[4][0]);
                acc[4][1] = fmaf(xb.x, ea.y, acc[4][1]);
                acc[4][2] = fmaf(xb.x, ea.z, acc[4][2]);
                acc[4][3] = fmaf(xb.x, ea.w, acc[4][3]);
                acc[4][4] = fmaf(xb.x, eb.x, acc[4][4]);
                acc[4][5] = fmaf(xb.x, eb.y, acc[4][5]);
                acc[4][6] = fmaf(xb.x, eb.z, acc[4][6]);
                acc[4][7] = fmaf(xb.x, eb.w, acc[4][7]);
                acc[5][0] = fmaf(xb.y, ea.x, acc[5][0]);
                acc[5][1] = fmaf(xb.y, ea.y, acc[5][1]);
                acc[5][2] = fmaf(xb.y, ea.z, acc[5][2]);
                acc[5][3] = fmaf(xb.y, ea.w, acc[5][3]);
                acc[5][4] = fmaf(xb.y, eb.x, acc[5][4]);
                acc[5][5] = fmaf(xb.y, eb.y, acc[5][5]);
                acc[5][6] = fmaf(xb.y, eb.z, acc[5][6]);
                acc[5][7] = fmaf(xb.y, eb.w, acc[5][7]);
                acc[6][0] = fmaf(xb.z, ea.x, acc[6][0]);
                acc[6][1] = fmaf(xb.z, ea.y, acc[6][1]);
                acc[6][2] = fmaf(xb.z, ea.z, acc[6][2]);
                acc[6][3] = fmaf(xb.z, ea.w, acc[6][3]);
                acc[6][4] = fmaf(xb.z, eb.x, acc[6][4]);
                acc[6][5] = fmaf(xb.z, eb.y, acc[6][5]);
                acc[6][6] = fmaf(xb.z, eb.z, acc[6][6]);
                acc[6][7] = fmaf(xb.z, eb.w, acc[6][7]);
                acc[7][0] = fmaf(xb.w, ea.x, acc[7][0]);
                acc[7][1] = fmaf(xb.w, ea.y, acc[7][1]);
                acc[7][2] = fmaf(xb.w, ea.z, acc[7][2]);
                acc[7][3] = fmaf(xb.w, ea.w, acc[7][3]);
                acc[7][4] = fmaf(xb.w, eb.x, acc[7][4]);
                acc[7][5] = fmaf(xb.w, eb.y, acc[7][5]);
                acc[7][6] = fmaf(xb.w, eb.z, acc[7][6]);
                acc[7][7] = fmaf(xb.w, eb.w, acc[7][7]);
            }
        }

        // ---- per-subtile epilogue: dist = cn - 2*dot, running argmin ----
        float cnv[8];
#pragma unroll
        for (int c = 0; c < 8; ++c)
            cnv[c] = cn[k0 + j4 + ((c < 4) ? c : 60 + c)];
#pragma unroll
        for (int r = 0; r < 8; ++r) {
#pragma unroll
            for (int c = 0; c < 8; ++c) {    // ascending k, strict <
                float dist = fmaf(-2.f, acc[r][c], cnv[c]);
                int   k    = k0 + j4 + ((c < 4) ? c : 60 + c);
                if (dist < bd[r]) { bd[r] = dist; bix[r] = k; }
                acc[r][c] = 0.f;
            }
        }
    }

    // ---- once per block: reduce across the 16 code lanes, write partial ----
#pragma unroll
    for (int r = 0; r < 8; ++r) {
        float d  = bd[r];
        int   i  = bix[r];
#pragma unroll
        for (int m = 1; m < 16; m <<= 1) {
            float od = __shfl_xor(d, m, 64);
            int   oi = __shfl_xor(i, m, 64);
            if (od < d || (od == d && oi < i)) { d = od; i = oi; }
        }
        if (jj == 0) {
            int lr = (r < 4) ? (g4 + r) : (64 + g4 + r - 4);
            pmin[kg * N_PIX + n0 + lr] = d;
            pidx[kg * N_PIX + n0 + lr] = i;
        }
    }
}

// ---------------------------------------------------------------------------
// Kernel 3: reduce 8 k-group partials per row, add ||x||^2, gather winning
// code column, write all three outputs.
// ---------------------------------------------------------------------------
__global__ __launch_bounds__(256)
void vq_finalize(const float* __restrict__ x,
                 const float* __restrict__ ec,
                 const float* __restrict__ pmin,
                 const int*   __restrict__ pidx,
                 float* __restrict__ out) {
    int n = blockIdx.x * 256 + threadIdx.x;   // 0..16383
    float best = 3.0e38f;
    int   bi   = 0x7fffffff;
#pragma unroll
    for (int kb = 0; kb < KGRP; ++kb) {
        float m = pmin[kb * N_PIX + n];
        int   i = pidx[kb * N_PIX + n];
        if (m < best || (m == best && i < bi)) { best = m; bi = i; }
    }
    float rn = 0.f;
#pragma unroll
    for (int d = 0; d < D_DIM; ++d) {
        float v = x[d * N_PIX + n];
        rn = fmaf(v, v, rn);
    }
    out[OUT_DMIN + n] = best + rn;
    out[OUT_IND  + n] = (float)bi;
#pragma unroll
    for (int d = 0; d < D_DIM; ++d)
        out[OUT_QUANT + d * N_PIX + n] = ec[d * K_CODES + bi];
}

// ---------------------------------------------------------------------------
extern "C" void kernel_launch(void* const* d_in, const int* in_sizes, int n_in,
                              void* d_out, int out_size, void* d_ws, size_t ws_size,
                              hipStream_t stream) {
    const float* x     = (const float*)d_in[0];   // [1,64,128,128]
    const float* embed = (const float*)d_in[1];   // [64,8193]
    const int*   cnt   = (const int*)d_in[2];     // [8192]
    float* out = (float*)d_out;

    // workspace layout
    float* ec   = (float*)d_ws;                                   // 2 MB
    float* cn   = (float*)((char*)d_ws + (size_t)2 * 1024 * 1024);   // 32 KB
    float* pmin = (float*)((char*)d_ws + (size_t)2 * 1024 * 1024 + 32768);
    int*   pidx = (int*)((char*)pmin + (size_t)KGRP * N_PIX * 4);

    vq_prep<<<K_CODES / 256, 256, 0, stream>>>(embed, cnt, ec, cn);
    vq_dist_tile<<<KGRP * 128, 256, 0, stream>>>(x, ec, cn, pmin, pidx);
    vq_finalize<<<N_PIX / 256, 256, 0, stream>>>(x, ec, pmin, pidx, out);
}